// Round 7
// baseline (195.885 us; speedup 1.0000x reference)
//
#include <hip/hip_runtime.h>
#include <hip/hip_bf16.h>

#define DI __device__ __forceinline__

namespace {
constexpr int N_ = 128, S_ = 32, P_ = 16, F_ = 256, H_ = 4, NH_ = 128;
constexpr int SP_ = S_ * P_;          // 512
constexpr int ROWS_ = N_ * SP_;       // 65536
constexpr int GC_ = H_ * NH_;         // 512
constexpr float SLOPE_ = 0.2f;
constexpr int OUT_ELEMS = N_ * SP_ * NH_;    // 8,388,608
}

DI float lrelu(float x) { return x >= 0.f ? x : SLOPE_ * x; }

DI unsigned short f2h(float x) {
    _Float16 h = (_Float16)x;
    return __builtin_bit_cast(unsigned short, h);
}
DI float h2f(unsigned short b) {
    return (float)__builtin_bit_cast(_Float16, b);
}

typedef _Float16 f16x8 __attribute__((ext_vector_type(8)));
typedef float    f32x4 __attribute__((ext_vector_type(4)));

DI f32x4 mfma16h(uint4 a, uint4 b, f32x4 c) {
    return __builtin_amdgcn_mfma_f32_16x16x32_f16(
        __builtin_bit_cast(f16x8, a), __builtin_bit_cast(f16x8, b), c, 0, 0, 0);
}

// ---------------------------------------------------------------------------
// prep: wl_s[f][h] = sum_nh W_l[f][h*128+nh]*aw[nh];  wr_s likewise with aw[128+]
__global__ __launch_bounds__(256) void prep_kernel(
    const float* __restrict__ Wl, const float* __restrict__ Wr,
    const float* __restrict__ aw, float* __restrict__ wls, float* __restrict__ wrs) {
    int t = blockIdx.x * 256 + threadIdx.x;   // 0..2047
    int which = t >> 10;                       // 0 -> wl, 1 -> wr
    int f = (t & 1023) >> 2;
    int h = t & 3;
    const float* W = which ? Wr : Wl;
    const float* a = aw + which * NH_;
    const float* wrow = W + (size_t)f * GC_ + h * NH_;
    float s = 0.f;
    for (int k = 0; k < NH_; ++k) s += wrow[k] * a[k];
    (which ? wrs : wls)[f * H_ + h] = s;
}

// ---------------------------------------------------------------------------
// prep_bt: split Wr*256 into f16 hi/lo in TRANSPOSED layout bt[col][k].
// x256 (exact power of 2, undone in gemm epilogue) keeps lo in f16 normal range.
__global__ __launch_bounds__(256) void prep_bt(
    const float* __restrict__ Wr, unsigned short* __restrict__ bth,
    unsigned short* __restrict__ btl) {
    int t = blockIdx.x * 256 + threadIdx.x;   // 0..16383
    int col = t >> 5, k0 = (t & 31) * 8;
    union { unsigned short us[8]; uint4 v; } ph, pl;
#pragma unroll
    for (int e = 0; e < 8; ++e) {
        float v = Wr[(size_t)(k0 + e) * GC_ + col] * 256.0f;
        unsigned short hi = f2h(v);
        ph.us[e] = hi;
        pl.us[e] = f2h(v - h2f(hi));
    }
    *(uint4*)&bth[col * F_ + k0] = ph.v;
    *(uint4*)&btl[col * F_ + k0] = pl.v;
}

// ---------------------------------------------------------------------------
// scores: one thread per row r = n*512 + sp of h.  sl/sr layout: [sp][n][h]
__global__ __launch_bounds__(256) void score_kernel(
    const float* __restrict__ hm, const float* __restrict__ wls,
    const float* __restrict__ wrs, float* __restrict__ sl, float* __restrict__ sr) {
    int r = blockIdx.x * 256 + threadIdx.x;    // 0..65535
    const float4* hr  = (const float4*)(hm + (size_t)r * F_);
    const float4* wl4 = (const float4*)wls;    // [f] -> 4 heads
    const float4* wr4 = (const float4*)wrs;
    float4 al = {0.f,0.f,0.f,0.f}, ar = {0.f,0.f,0.f,0.f};
    for (int f0 = 0; f0 < F_; f0 += 4) {
        float4 hv = hr[f0 >> 2];
        float hx[4] = {hv.x, hv.y, hv.z, hv.w};
#pragma unroll
        for (int u = 0; u < 4; ++u) {
            float4 wl = wl4[f0 + u], wr = wr4[f0 + u];
            al.x += hx[u] * wl.x; al.y += hx[u] * wl.y;
            al.z += hx[u] * wl.z; al.w += hx[u] * wl.w;
            ar.x += hx[u] * wr.x; ar.y += hx[u] * wr.y;
            ar.z += hx[u] * wr.z; ar.w += hx[u] * wr.w;
        }
    }
    int n = r >> 9, sp = r & 511;
    ((float4*)sl)[sp * N_ + n] = al;
    ((float4*)sr)[sp * N_ + n] = ar;
}

// ---------------------------------------------------------------------------
// g_r GEMM via split-f16 MFMA, node-tiled: block rb = sp; A rows = nodes
// (hm rows node*512+rb), D = [128 nodes x 512 cols] written TRANSPOSED:
// gT[sp][col][node] (contiguous 128 KB slab per sp).
__global__ __launch_bounds__(512) void gemm_mfma(
    const float* __restrict__ hm, const unsigned short* __restrict__ bth,
    const unsigned short* __restrict__ btl, unsigned short* __restrict__ gT) {
    constexpr int PA = 72;
    __shared__ unsigned short Ahi[128 * PA];
    __shared__ unsigned short Alo[128 * PA];

    int rb = blockIdx.x;                 // sp index 0..511
    int t = threadIdx.x;
    int w = t >> 6, l = t & 63;
    int colw = w * 64;
    int ls = l & 15, kg = l >> 4;

    f32x4 acc[8][4];
#pragma unroll
    for (int m = 0; m < 8; ++m)
#pragma unroll
        for (int n = 0; n < 4; ++n) acc[m][n] = (f32x4){0.f, 0.f, 0.f, 0.f};

    for (int step = 0; step < 4; ++step) {
        int k0s = step * 64;
        if (step) __syncthreads();
        // stage A-tile: 128 node-rows x 64 k, hi/lo f16
#pragma unroll
        for (int u = 0; u < 2; ++u) {
            int gi = t + u * 512;
            int row = gi >> 3, kc = (gi & 7) * 8;   // row = node
            const float* ap = hm + ((size_t)row * 512 + rb) * F_ + k0s + kc;
            float4 a0 = *(const float4*)ap;
            float4 a1 = *(const float4*)(ap + 4);
            float av[8] = {a0.x, a0.y, a0.z, a0.w, a1.x, a1.y, a1.z, a1.w};
            union { unsigned short us[8]; uint4 v; } ph, pl;
#pragma unroll
            for (int e = 0; e < 8; ++e) {
                unsigned short hi = f2h(av[e]);
                ph.us[e] = hi;
                pl.us[e] = f2h(av[e] - h2f(hi));
            }
            *(uint4*)&Ahi[row * PA + kc] = ph.v;
            *(uint4*)&Alo[row * PA + kc] = pl.v;
        }
        __syncthreads();

#pragma unroll
        for (int half = 0; half < 2; ++half) {
            int kglob = k0s + half * 32 + kg * 8;
            int kloc  = half * 32 + kg * 8;
            uint4 fbh[4], fbl[4];
#pragma unroll
            for (int n = 0; n < 4; ++n) {
                int c = colw + n * 16 + ls;
                fbh[n] = *(const uint4*)&bth[(size_t)c * F_ + kglob];
                fbl[n] = *(const uint4*)&btl[(size_t)c * F_ + kglob];
            }
#pragma unroll
            for (int m = 0; m < 8; ++m) {
                int row = m * 16 + ls;
                uint4 fah = *(const uint4*)&Ahi[row * PA + kloc];
                uint4 fal = *(const uint4*)&Alo[row * PA + kloc];
#pragma unroll
                for (int n = 0; n < 4; ++n) {
                    acc[m][n] = mfma16h(fah, fbh[n], acc[m][n]);   // hi*hi
                    acc[m][n] = mfma16h(fah, fbl[n], acc[m][n]);   // hiA*loB
                    acc[m][n] = mfma16h(fal, fbh[n], acc[m][n]);   // loA*hiB
                }
            }
        }
    }

    // epilogue: D[node][col]; lane q-quad = 4 consecutive nodes at fixed col.
    // gT[sp][col][node], undo x256 scale.
    unsigned short* gr = gT + (size_t)rb * 65536;
#pragma unroll
    for (int m = 0; m < 8; ++m) {
        int nodeb = m * 16 + kg * 4;
#pragma unroll
        for (int n = 0; n < 4; ++n) {
            int c = colw + n * 16 + ls;
            union { unsigned short us[4]; uint2 v; } pk;
#pragma unroll
            for (int q = 0; q < 4; ++q) pk.us[q] = f2h(acc[m][n][q] * 0.00390625f);
            *(uint2*)(gr + (size_t)c * 128 + nodeb) = pk.v;
        }
    }
}

// ---------------------------------------------------------------------------
// Fused softmax + PV: one block per sp (512 thr, 8 waves, wave tile 64i x 32f).
// No G staging: B-fragments load directly from gT[sp][col][node] (L2/L3).
// LDS ~43 KB -> 3 blocks/CU.
__global__ __launch_bounds__(512) void smpv_kernel(
    const float* __restrict__ sl_g, const float* __restrict__ sr_g,
    const unsigned short* __restrict__ gT,
    float* __restrict__ a_out, float* __restrict__ out) {
    constexpr int PH = 136;
    __shared__ unsigned short ah[128 * PH];
    __shared__ float4 sl4[N_], sr4[N_], mrow[N_], invs[N_];
    __shared__ float mx1[H_], mx2[H_];
    __shared__ int   id1[H_];

    int sp = blockIdx.x;
    int t = threadIdx.x;
    int w = t >> 6, l = t & 63;
    int i0  = (w & 1) * 64;              // wave tile: 64 i x 32 f
    int f0w = (w >> 1) * 32;
    int ls = l & 15, kg = l >> 4;

    if (t < 128)       sl4[t]       = ((const float4*)sl_g)[sp * N_ + t];
    else if (t < 256)  sr4[t - 128] = ((const float4*)sr_g)[sp * N_ + (t - 128)];
    __syncthreads();

    if (t < H_) {
        float m1 = -1e30f; int i1 = 0;
        for (int j = 0; j < N_; ++j) {
            float v = ((const float*)&sl4[j])[t];
            if (v > m1) { m1 = v; i1 = j; }
        }
        float m2 = -1e30f;
        for (int j = 0; j < N_; ++j)
            if (j != i1) m2 = fmaxf(m2, ((const float*)&sl4[j])[t]);
        mx1[t] = m1; mx2[t] = m2; id1[t] = i1;
    }
    __syncthreads();

    {   // pass 1: per-(i,h) max (monotonicity) and inv-sum
        int i = t & 127, h = t >> 7;
        float sri = ((const float*)&sr4[i])[h];
        float m = lrelu(sri + ((id1[h] == i) ? mx2[h] : mx1[h]));
        float sum = 0.f;
        for (int j = 0; j < N_; ++j) {
            float e = lrelu(sri + ((const float*)&sl4[j])[h]);
            float p = __expf(e - m);
            if (j != i) sum += p;
        }
        ((float*)&mrow[i])[h] = m;
        ((float*)&invs[i])[h] = 1.f / sum;
    }
    __syncthreads();

    const unsigned short* gT_base = gT + (size_t)sp * 65536;
    float4* a_base = (float4*)(a_out + (size_t)sp * 65536);

    f32x4 acc[4][2];
#pragma unroll
    for (int m = 0; m < 4; ++m)
#pragma unroll
        for (int n = 0; n < 2; ++n) acc[m][n] = (f32x4){0.f, 0.f, 0.f, 0.f};

    for (int h = 0; h < H_; ++h) {
        if (h) __syncthreads();

        {   // a-tile compute + f16 LDS deposit (+ coalesced a_out write on h==0)
            int i = t >> 2, j0 = (t & 3) * 32;
            float4 srv = sr4[i], m4 = mrow[i], s4 = invs[i];
            if (h == 0) {
#pragma unroll
                for (int u = 0; u < 4; ++u) {
                    union { unsigned short us[8]; uint4 v; } pk;
#pragma unroll
                    for (int e = 0; e < 8; ++e) {
                        int j = j0 + u * 8 + e;
                        float4 slv = sl4[j];
                        float4 p;
                        p.x = __expf(lrelu(srv.x + slv.x) - m4.x) * s4.x;
                        p.y = __expf(lrelu(srv.y + slv.y) - m4.y) * s4.y;
                        p.z = __expf(lrelu(srv.z + slv.z) - m4.z) * s4.z;
                        p.w = __expf(lrelu(srv.w + slv.w) - m4.w) * s4.w;
                        if (j == i) { p.x = 0.f; p.y = 0.f; p.z = 0.f; p.w = 0.f; }
                        a_base[i * N_ + j] = p;
                        pk.us[e] = f2h(p.x);
                    }
                    *(uint4*)&ah[i * PH + j0 + u * 8] = pk.v;
                }
            } else {
                float sri = ((const float*)&srv)[h];
                float m = ((const float*)&m4)[h], s = ((const float*)&s4)[h];
#pragma unroll
                for (int u = 0; u < 4; ++u) {
                    union { unsigned short us[8]; uint4 v; } pk;
#pragma unroll
                    for (int e = 0; e < 8; ++e) {
                        int j = j0 + u * 8 + e;
                        float p = (j == i) ? 0.f
                                : __expf(lrelu(sri + ((const float*)&sl4[j])[h]) - m) * s;
                        pk.us[e] = f2h(p);
                    }
                    *(uint4*)&ah[i * PH + j0 + u * 8] = pk.v;
                }
            }
        }
        __syncthreads();

        // MFMA: K = 128 over j; B-fragments direct from gT (global, L2-hot)
#pragma unroll
        for (int k0 = 0; k0 < 128; k0 += 32) {
            int koff = k0 + 8 * kg;
            uint4 fah[4], fbv[2];
#pragma unroll
            for (int m = 0; m < 4; ++m) {
                int row = i0 + m * 16 + ls;
                fah[m] = *(const uint4*)&ah[row * PH + koff];
            }
#pragma unroll
            for (int n = 0; n < 2; ++n) {
                int f = f0w + n * 16 + ls;
                fbv[n] = *(const uint4*)&gT_base[(size_t)(h * NH_ + f) * 128 + koff];
            }
#pragma unroll
            for (int m = 0; m < 4; ++m)
#pragma unroll
                for (int n = 0; n < 2; ++n)
                    acc[m][n] = mfma16h(fah[m], fbv[n], acc[m][n]);
        }
    }

    // epilogue: D[i][f]: lane q-quad = 4 consecutive i at fixed f
    int g4 = kg * 4;
    int c  = ls;
#pragma unroll
    for (int m = 0; m < 4; ++m) {
        int ibase = i0 + m * 16 + g4;
#pragma unroll
        for (int n = 0; n < 2; ++n) {
            int f = f0w + n * 16 + c;
#pragma unroll
            for (int q = 0; q < 4; ++q)
                out[(size_t)(ibase + q) * 65536 + (size_t)sp * NH_ + f] = acc[m][n][q] * 0.25f;
        }
    }
}

// ---------------------------------------------------------------------------
extern "C" void kernel_launch(void* const* d_in, const int* in_sizes, int n_in,
                              void* d_out, int out_size, void* d_ws, size_t ws_size,
                              hipStream_t stream) {
    const float* hm = (const float*)d_in[0];
    const float* Wl = (const float*)d_in[1];
    const float* Wr = (const float*)d_in[2];
    const float* aw = (const float*)d_in[3];

    float* out   = (float*)d_out;
    float* a_out = out + OUT_ELEMS;

    char* ws = (char*)d_ws;
    unsigned short* gT = (unsigned short*)ws;             // 64 MiB f16 [sp][col][node]
    float* sl  = (float*)(ws + (size_t)67108864);
    float* sr  = sl + SP_ * N_ * H_;
    float* wls = sr + SP_ * N_ * H_;
    float* wrs = wls + F_ * H_;
    unsigned short* bth = (unsigned short*)(ws + (size_t)67108864 + 2113536);
    unsigned short* btl = bth + GC_ * F_;                 // 512*256 each

    prep_kernel   <<<8,           256, 0, stream>>>(Wl, Wr, aw, wls, wrs);
    prep_bt       <<<64,          256, 0, stream>>>(Wr, bth, btl);
    score_kernel  <<<ROWS_ / 256, 256, 0, stream>>>(hm, wls, wrs, sl, sr);
    gemm_mfma     <<<512,         512, 0, stream>>>(hm, bth, btl, gT);
    smpv_kernel   <<<SP_,         512, 0, stream>>>(sl, sr, gT, a_out, out);
}

// Round 8
// 180.306 us; speedup vs baseline: 1.0864x; 1.0864x over previous
//
#include <hip/hip_runtime.h>
#include <hip/hip_bf16.h>

#define DI __device__ __forceinline__

namespace {
constexpr int N_ = 128, S_ = 32, P_ = 16, F_ = 256, H_ = 4, NH_ = 128;
constexpr int SP_ = S_ * P_;          // 512
constexpr int ROWS_ = N_ * SP_;       // 65536
constexpr int GC_ = H_ * NH_;         // 512
constexpr float SLOPE_ = 0.2f;
constexpr int OUT_ELEMS = N_ * SP_ * NH_;    // 8,388,608
}

DI float lrelu(float x) { return x >= 0.f ? x : SLOPE_ * x; }

DI unsigned short f2h(float x) {
    _Float16 h = (_Float16)x;
    return __builtin_bit_cast(unsigned short, h);
}
DI float h2f(unsigned short b) {
    return (float)__builtin_bit_cast(_Float16, b);
}

typedef _Float16 f16x8 __attribute__((ext_vector_type(8)));
typedef float    f32x4 __attribute__((ext_vector_type(4)));

DI f32x4 mfma16h(uint4 a, uint4 b, f32x4 c) {
    return __builtin_amdgcn_mfma_f32_16x16x32_f16(
        __builtin_bit_cast(f16x8, a), __builtin_bit_cast(f16x8, b), c, 0, 0, 0);
}

// ---------------------------------------------------------------------------
// prep: wl_s[f][h] = sum_nh W_l[f][h*128+nh]*aw[nh];  wr_s likewise with aw[128+]
__global__ __launch_bounds__(256) void prep_kernel(
    const float* __restrict__ Wl, const float* __restrict__ Wr,
    const float* __restrict__ aw, float* __restrict__ wls, float* __restrict__ wrs) {
    int t = blockIdx.x * 256 + threadIdx.x;   // 0..2047
    int which = t >> 10;                       // 0 -> wl, 1 -> wr
    int f = (t & 1023) >> 2;
    int h = t & 3;
    const float* W = which ? Wr : Wl;
    const float* a = aw + which * NH_;
    const float* wrow = W + (size_t)f * GC_ + h * NH_;
    float s = 0.f;
    for (int k = 0; k < NH_; ++k) s += wrow[k] * a[k];
    (which ? wrs : wls)[f * H_ + h] = s;
}

// ---------------------------------------------------------------------------
// prep_bt: split Wr*256 into f16 hi/lo in TRANSPOSED layout bt[col][k].
// x256 (exact power of 2, undone in gemm epilogue) keeps lo in f16 normal range.
__global__ __launch_bounds__(256) void prep_bt(
    const float* __restrict__ Wr, unsigned short* __restrict__ bth,
    unsigned short* __restrict__ btl) {
    int t = blockIdx.x * 256 + threadIdx.x;   // 0..16383
    int col = t >> 5, k0 = (t & 31) * 8;
    union { unsigned short us[8]; uint4 v; } ph, pl;
#pragma unroll
    for (int e = 0; e < 8; ++e) {
        float v = Wr[(size_t)(k0 + e) * GC_ + col] * 256.0f;
        unsigned short hi = f2h(v);
        ph.us[e] = hi;
        pl.us[e] = f2h(v - h2f(hi));
    }
    *(uint4*)&bth[col * F_ + k0] = ph.v;
    *(uint4*)&btl[col * F_ + k0] = pl.v;
}

// ---------------------------------------------------------------------------
// scores: one thread per row r = n*512 + sp of h.  sl/sr layout: [sp][n][h]
__global__ __launch_bounds__(256) void score_kernel(
    const float* __restrict__ hm, const float* __restrict__ wls,
    const float* __restrict__ wrs, float* __restrict__ sl, float* __restrict__ sr) {
    int r = blockIdx.x * 256 + threadIdx.x;    // 0..65535
    const float4* hr  = (const float4*)(hm + (size_t)r * F_);
    const float4* wl4 = (const float4*)wls;    // [f] -> 4 heads
    const float4* wr4 = (const float4*)wrs;
    float4 al = {0.f,0.f,0.f,0.f}, ar = {0.f,0.f,0.f,0.f};
    for (int f0 = 0; f0 < F_; f0 += 4) {
        float4 hv = hr[f0 >> 2];
        float hx[4] = {hv.x, hv.y, hv.z, hv.w};
#pragma unroll
        for (int u = 0; u < 4; ++u) {
            float4 wl = wl4[f0 + u], wr = wr4[f0 + u];
            al.x += hx[u] * wl.x; al.y += hx[u] * wl.y;
            al.z += hx[u] * wl.z; al.w += hx[u] * wl.w;
            ar.x += hx[u] * wr.x; ar.y += hx[u] * wr.y;
            ar.z += hx[u] * wr.z; ar.w += hx[u] * wr.w;
        }
    }
    int n = r >> 9, sp = r & 511;
    ((float4*)sl)[sp * N_ + n] = al;
    ((float4*)sr)[sp * N_ + n] = ar;
}

// ---------------------------------------------------------------------------
// Fully fused per-sp kernel: GEMM (g in LDS) + softmax + a_out + PV + out.
// 512 threads (8 waves). GEMM: wave w owns cols w*64..+64, all 128 node rows.
// PV: wave w owns rows w*16..+16, all 128 f; P lives in registers (no LDS, no
// barriers inside the PV loop).
__global__ __launch_bounds__(512) void gat_fused(
    const float* __restrict__ sl_g, const float* __restrict__ sr_g,
    const float* __restrict__ hm,
    const unsigned short* __restrict__ bth, const unsigned short* __restrict__ btl,
    float* __restrict__ a_out, float* __restrict__ out) {
    constexpr int PA = 40;                       // 80B rows: 16B-aligned
    __shared__ unsigned short Ahi[128 * PA];     // 10240 B
    __shared__ unsigned short Alo[128 * PA];     // 10240 B
    __shared__ unsigned short gt[512 * 128];     // g^T [col][node], 131072 B
    __shared__ float4 sl4[N_], sr4[N_], mrow[N_], invs[N_];   // 8192 B
    __shared__ float mx1[H_], mx2[H_];
    __shared__ int   id1[H_];

    int sp = blockIdx.x;
    int t = threadIdx.x;
    int w = t >> 6, l = t & 63;
    int ls = l & 15, kg = l >> 4;

    // ---- load scores ----
    if (t < 128)       sl4[t]       = ((const float4*)sl_g)[sp * N_ + t];
    else if (t < 256)  sr4[t - 128] = ((const float4*)sr_g)[sp * N_ + (t - 128)];
    __syncthreads();

    // ---- per-head max1/max2 of sl (diag-aware row max via monotonicity) ----
    if (t < H_) {
        float m1 = -1e30f; int i1 = 0;
        for (int j = 0; j < N_; ++j) {
            float v = ((const float*)&sl4[j])[t];
            if (v > m1) { m1 = v; i1 = j; }
        }
        float m2 = -1e30f;
        for (int j = 0; j < N_; ++j)
            if (j != i1) m2 = fmaxf(m2, ((const float*)&sl4[j])[t]);
        mx1[t] = m1; mx2[t] = m2; id1[t] = i1;
    }
    __syncthreads();

    // ---- pass 1: per-(i,h) row max and inv-sum ----
    {
        int i = t & 127, h = t >> 7;
        float sri = ((const float*)&sr4[i])[h];
        float m = lrelu(sri + ((id1[h] == i) ? mx2[h] : mx1[h]));
        float sum = 0.f;
        for (int j = 0; j < N_; ++j) {
            float e = lrelu(sri + ((const float*)&sl4[j])[h]);
            float p = __expf(e - m);
            if (j != i) sum += p;
        }
        ((float*)&mrow[i])[h] = m;
        ((float*)&invs[i])[h] = 1.f / sum;
    }
    __syncthreads();

    // ---- a_out write phase (fire-and-forget; drains under the GEMM) ----
    {
        float4* a_base = (float4*)(a_out + (size_t)sp * 65536);
        int i = t >> 2, j0 = (t & 3) * 32;
        float4 srv = sr4[i], m4 = mrow[i], s4 = invs[i];
#pragma unroll
        for (int u = 0; u < 4; ++u) {
#pragma unroll
            for (int e = 0; e < 8; ++e) {
                int j = j0 + u * 8 + e;
                float4 slv = sl4[j];
                float4 p;
                p.x = __expf(lrelu(srv.x + slv.x) - m4.x) * s4.x;
                p.y = __expf(lrelu(srv.y + slv.y) - m4.y) * s4.y;
                p.z = __expf(lrelu(srv.z + slv.z) - m4.z) * s4.z;
                p.w = __expf(lrelu(srv.w + slv.w) - m4.w) * s4.w;
                if (j == i) { p.x = 0.f; p.y = 0.f; p.z = 0.f; p.w = 0.f; }
                a_base[i * N_ + j] = p;
            }
        }
    }

    // ---- GEMM: g = (hm rows of this sp) @ Wr, split-f16, acc fp32 ----
    int colw = w * 64;
    f32x4 acc[8][4];
#pragma unroll
    for (int m = 0; m < 8; ++m)
#pragma unroll
        for (int n = 0; n < 4; ++n) acc[m][n] = (f32x4){0.f, 0.f, 0.f, 0.f};

    for (int step = 0; step < 8; ++step) {
        int k0s = step * 32;
        if (step) __syncthreads();
        {   // stage A-tile: 128 node rows x 32 k, hi/lo f16
            int row = t >> 2, kc = (t & 3) * 8;
            const float* ap = hm + ((size_t)row * 512 + sp) * 256 + k0s + kc;
            float4 a0 = *(const float4*)ap;
            float4 a1 = *(const float4*)(ap + 4);
            float av[8] = {a0.x, a0.y, a0.z, a0.w, a1.x, a1.y, a1.z, a1.w};
            union { unsigned short us[8]; uint4 v; } ph, pl;
#pragma unroll
            for (int e = 0; e < 8; ++e) {
                unsigned short hi = f2h(av[e]);
                ph.us[e] = hi;
                pl.us[e] = f2h(av[e] - h2f(hi));
            }
            *(uint4*)&Ahi[row * PA + kc] = ph.v;
            *(uint4*)&Alo[row * PA + kc] = pl.v;
        }
        __syncthreads();

        int kglob = k0s + kg * 8;
        int kloc  = kg * 8;
        uint4 fbh[4], fbl[4];
#pragma unroll
        for (int n = 0; n < 4; ++n) {
            int c = colw + n * 16 + ls;
            fbh[n] = *(const uint4*)&bth[(size_t)c * F_ + kglob];
            fbl[n] = *(const uint4*)&btl[(size_t)c * F_ + kglob];
        }
#pragma unroll
        for (int m = 0; m < 8; ++m) {
            int row = m * 16 + ls;
            uint4 fah = *(const uint4*)&Ahi[row * PA + kloc];
            uint4 fal = *(const uint4*)&Alo[row * PA + kloc];
#pragma unroll
            for (int n = 0; n < 4; ++n) {
                acc[m][n] = mfma16h(fah, fbh[n], acc[m][n]);   // hi*hi
                acc[m][n] = mfma16h(fah, fbl[n], acc[m][n]);   // hiA*loB
                acc[m][n] = mfma16h(fal, fbh[n], acc[m][n]);   // loA*hiB
            }
        }
    }

    // ---- GEMM epilogue -> gt[col][node ^ swz] in LDS (undo x256) ----
#pragma unroll
    for (int m = 0; m < 8; ++m) {
        int nodeb = m * 16 + kg * 4;
#pragma unroll
        for (int n = 0; n < 4; ++n) {
            int c = colw + n * 16 + ls;
            union { unsigned short us[4]; uint2 v; } pk;
#pragma unroll
            for (int q = 0; q < 4; ++q) pk.us[q] = f2h(acc[m][n][q] * 0.00390625f);
            *(uint2*)&gt[c * 128 + (nodeb ^ ((c & 7) << 3))] = pk.v;
        }
    }
    __syncthreads();

    // ---- PV: rows in registers, B from gt (LDS). No barriers needed. ----
    f32x4 aco[8];
#pragma unroll
    for (int n = 0; n < 8; ++n) aco[n] = (f32x4){0.f, 0.f, 0.f, 0.f};

    int i_my = w * 16 + ls;
    for (int h = 0; h < H_; ++h) {
        float sri = ((const float*)&sr4[i_my])[h];
        float mh  = ((const float*)&mrow[i_my])[h];
        float sh  = ((const float*)&invs[i_my])[h];
        uint4 pa[4];
#pragma unroll
        for (int k0i = 0; k0i < 4; ++k0i) {
            int jb = k0i * 32 + kg * 8;
            union { unsigned short us[8]; uint4 v; } pk;
#pragma unroll
            for (int e = 0; e < 8; ++e) {
                int j = jb + e;
                float p = (j == i_my) ? 0.f
                        : __expf(lrelu(sri + ((const float*)&sl4[j])[h]) - mh) * sh;
                pk.us[e] = f2h(p);
            }
            pa[k0i] = pk.v;
        }
#pragma unroll
        for (int k0i = 0; k0i < 4; ++k0i) {
            int koff = k0i * 32 + kg * 8;
#pragma unroll
            for (int n = 0; n < 8; ++n) {
                int f = n * 16 + ls;
                uint4 fb = *(const uint4*)&gt[(size_t)(h * NH_ + f) * 128 +
                                              (koff ^ ((f & 7) << 3))];
                aco[n] = mfma16h(pa[k0i], fb, aco[n]);
            }
        }
    }

    // ---- out epilogue: D row = w*16 + kg*4 + q, col f = n*16 + ls ----
#pragma unroll
    for (int n = 0; n < 8; ++n) {
        int f = n * 16 + ls;
#pragma unroll
        for (int q = 0; q < 4; ++q)
            out[(size_t)(w * 16 + kg * 4 + q) * 65536 + (size_t)sp * NH_ + f] =
                aco[n][q] * 0.25f;
    }
}

// ---------------------------------------------------------------------------
extern "C" void kernel_launch(void* const* d_in, const int* in_sizes, int n_in,
                              void* d_out, int out_size, void* d_ws, size_t ws_size,
                              hipStream_t stream) {
    const float* hm = (const float*)d_in[0];
    const float* Wl = (const float*)d_in[1];
    const float* Wr = (const float*)d_in[2];
    const float* aw = (const float*)d_in[3];

    float* out   = (float*)d_out;
    float* a_out = out + OUT_ELEMS;

    char* ws = (char*)d_ws;
    float* sl  = (float*)ws;                              // 1 MiB
    float* sr  = sl + SP_ * N_ * H_;                      // 1 MiB
    float* wls = sr + SP_ * N_ * H_;                      // 4 KiB
    float* wrs = wls + F_ * H_;                           // 4 KiB
    unsigned short* bth = (unsigned short*)(wrs + F_ * H_);   // 256 KiB
    unsigned short* btl = bth + GC_ * F_;                     // 256 KiB

    prep_kernel <<<8,           256, 0, stream>>>(Wl, Wr, aw, wls, wrs);
    prep_bt     <<<64,          256, 0, stream>>>(Wr, bth, btl);
    score_kernel<<<ROWS_ / 256, 256, 0, stream>>>(hm, wls, wrs, sl, sr);
    gat_fused   <<<SP_,         512, 0, stream>>>(sl, sr, hm, bth, btl, a_out, out);
}